// Round 1
// baseline (7421.146 us; speedup 1.0000x reference)
//
#include <hip/hip_runtime.h>
#include <math.h>

#define TT 1024
#define DD 384
#define NH 6
#define KK 64
#define DI 768
#define MH 12
#define HD 64
#define DS 64
#define NL 8
#define XDIM 1676   // 2*DI + 2*DS + MH
#define CONVC 896   // DI + 2*DS
#define NV 32000

// ---------------- helpers ----------------
__device__ __forceinline__ float siluf(float x) { return x / (1.f + expf(-x)); }
__device__ __forceinline__ float sigmoidf_(float x) { return 1.f / (1.f + expf(-x)); }

// ---------------- GEMM: C[M,N] = A[M,Kd] @ B, BT=0: B[Kd,N]; BT=1: B[N,Kd] ----------------
template<int BT>
__global__ __launch_bounds__(256) void gemm_kernel(
    const float* __restrict__ A, const float* __restrict__ B,
    float* __restrict__ C, int M, int N, int Kd)
{
  __shared__ __align__(16) float As[16][64];
  __shared__ __align__(16) float Bs[16][64];
  int tid = threadIdx.x;
  int m0 = blockIdx.y * 64, n0 = blockIdx.x * 64;
  int ty = tid >> 4, tx = tid & 15;
  float acc[4][4];
#pragma unroll
  for (int i = 0; i < 4; i++)
#pragma unroll
    for (int j = 0; j < 4; j++) acc[i][j] = 0.f;

  for (int k0 = 0; k0 < Kd; k0 += 16) {
    {
      int r = tid >> 2, c = (tid & 3) * 4;
      float4 av = *reinterpret_cast<const float4*>(A + (size_t)(m0 + r) * Kd + k0 + c);
      As[c + 0][r] = av.x; As[c + 1][r] = av.y; As[c + 2][r] = av.z; As[c + 3][r] = av.w;
    }
    if (BT == 0) {
      int r = tid >> 4, c = (tid & 15) * 4;
      float4 bv = make_float4(0.f, 0.f, 0.f, 0.f);
      if (n0 + c < N) bv = *reinterpret_cast<const float4*>(B + (size_t)(k0 + r) * N + n0 + c);
      *reinterpret_cast<float4*>(&Bs[r][c]) = bv;
    } else {
      int r = tid >> 2, c = (tid & 3) * 4;   // r: n-index, c: k-offset
      float4 bv = make_float4(0.f, 0.f, 0.f, 0.f);
      if (n0 + r < N) bv = *reinterpret_cast<const float4*>(B + (size_t)(n0 + r) * Kd + k0 + c);
      Bs[c + 0][r] = bv.x; Bs[c + 1][r] = bv.y; Bs[c + 2][r] = bv.z; Bs[c + 3][r] = bv.w;
    }
    __syncthreads();
#pragma unroll
    for (int kk = 0; kk < 16; ++kk) {
      float4 a4 = *reinterpret_cast<const float4*>(&As[kk][ty * 4]);
      float4 b4 = *reinterpret_cast<const float4*>(&Bs[kk][tx * 4]);
      float a[4] = {a4.x, a4.y, a4.z, a4.w};
      float b[4] = {b4.x, b4.y, b4.z, b4.w};
#pragma unroll
      for (int i = 0; i < 4; i++)
#pragma unroll
        for (int j = 0; j < 4; j++) acc[i][j] = fmaf(a[i], b[j], acc[i][j]);
    }
    __syncthreads();
  }
#pragma unroll
  for (int i = 0; i < 4; i++) {
    int m = m0 + ty * 4 + i;
#pragma unroll
    for (int j = 0; j < 4; j++) {
      int n = n0 + tx * 4 + j;
      if (n < N) C[(size_t)m * N + n] = acc[i][j];
    }
  }
}

// ---------------- embedding gather ----------------
__global__ void embed_kernel(const int* __restrict__ x, const float* __restrict__ embed,
                             float* __restrict__ h)
{
  int idx = blockIdx.x * 256 + threadIdx.x;
  if (idx < TT * DD) {
    int t = idx / DD, d = idx % DD;
    h[idx] = embed[(size_t)x[t] * DD + d];
  }
}

// ---------------- RMSNorm (generic over ncol) ----------------
__global__ __launch_bounds__(256) void rms_kernel(const float* __restrict__ in,
                                                  const float* __restrict__ w,
                                                  float* __restrict__ out, int ncol, float eps)
{
  int t = blockIdx.x;
  const float* row = in + (size_t)t * ncol;
  float ss = 0.f;
  for (int c = threadIdx.x; c < ncol; c += 256) { float v = row[c]; ss = fmaf(v, v, ss); }
  __shared__ float red[256];
  red[threadIdx.x] = ss; __syncthreads();
  for (int s = 128; s > 0; s >>= 1) {
    if (threadIdx.x < s) red[threadIdx.x] += red[threadIdx.x + s];
    __syncthreads();
  }
  float scale = rsqrtf(red[0] / ncol + eps);
  for (int c = threadIdx.x; c < ncol; c += 256) out[(size_t)t * ncol + c] = w[c] * row[c] * scale;
}

// ---------------- RWKV decay = exp(-exp(w + bias)) ----------------
__global__ void decay_kernel(float* __restrict__ wbuf, const float* __restrict__ wb)
{
  int idx = blockIdx.x * 256 + threadIdx.x;
  if (idx < TT * DD) {
    int d = idx % DD;
    wbuf[idx] = expf(-expf(wbuf[idx] + wb[d]));
  }
}

// ---------------- fused sequential scans: blocks 0..5 RWKV heads, 6..17 Mamba heads ----------------
__device__ __forceinline__ void rwkv_scan_body(int h, int tid,
    const float* __restrict__ rb, const float* __restrict__ kb,
    const float* __restrict__ vb, const float* __restrict__ db,
    const float* __restrict__ u, float* __restrict__ ob, float* smem)
{
  float* sbuf = smem;          // [2][4][64]
  float* us = smem + 512;      // [64]
  if (tid < 64) us[tid] = u[h * 64 + tid];
  int wv = tid >> 6, l = tid & 63;
  int vv = wv * 16 + (l & 15);
  int kc = l >> 4;
  int arr = tid >> 6, idx = tid & 63;
  const float* src = (arr == 0) ? rb : (arr == 1) ? kb : (arr == 2) ? db : vb;
  size_t base = (size_t)h * 64 + idx;
  float S[16];
#pragma unroll
  for (int i = 0; i < 16; i++) S[i] = 0.f;
  float reg = src[base];
  for (int t = 0; t < TT; ++t) {
    float* cb = sbuf + (t & 1) * 256;
    cb[arr * 64 + idx] = reg;
    if (t + 1 < TT) reg = src[(size_t)(t + 1) * DD + base];
    __syncthreads();
    float vt = cb[192 + vv];
    float acc = 0.f;
#pragma unroll
    for (int i = 0; i < 16; ++i) {
      int kkk = kc * 16 + i;
      float kv_ = cb[64 + kkk] * vt;
      acc = fmaf(cb[kkk], fmaf(us[kkk], kv_, S[i]), acc);
      S[i] = fmaf(cb[128 + kkk], S[i], kv_);
    }
    acc += __shfl_xor(acc, 16);
    acc += __shfl_xor(acc, 32);
    if (l < 16) ob[(size_t)t * DD + h * 64 + vv] = acc;
  }
}

__device__ __forceinline__ void mamba_scan_body(int hh, int tid,
    const float* __restrict__ xbc, const float* __restrict__ dtb,
    const float* __restrict__ Alog, const float* __restrict__ Dpw,
    float* __restrict__ yb, float* smem)
{
  float* sbuf = smem;          // [2][4][64], slot3[0] = dt
  int wv = tid >> 6, l = tid & 63;
  int p = wv * 16 + (l & 15);
  int sc = l >> 4;
  int arr = tid >> 6, idx = tid & 63;
  float A = -expf(Alog[hh]);
  float Dph = Dpw[hh];
  int off = (arr == 0) ? (hh * 64 + idx) : (arr == 1) ? (DI + idx) : (DI + DS + idx);
  float S[16];
#pragma unroll
  for (int i = 0; i < 16; i++) S[i] = 0.f;
  float reg = (arr < 3) ? xbc[off] : dtb[hh];
  for (int t = 0; t < TT; ++t) {
    float* cb = sbuf + (t & 1) * 256;
    if (arr < 3) cb[arr * 64 + idx] = reg;
    else if (idx == 0) cb[192] = reg;
    if (t + 1 < TT) reg = (arr < 3) ? xbc[(size_t)(t + 1) * CONVC + off]
                                    : dtb[(size_t)(t + 1) * MH + hh];
    __syncthreads();
    float dt_ = cb[192];
    float dA = expf(dt_ * A);
    float xp = cb[p];
    float dtx = dt_ * xp;
    float acc = 0.f;
#pragma unroll
    for (int i = 0; i < 16; ++i) {
      int s = sc * 16 + i;
      S[i] = fmaf(dA, S[i], dtx * cb[64 + s]);
      acc = fmaf(S[i], cb[128 + s], acc);
    }
    acc += __shfl_xor(acc, 16);
    acc += __shfl_xor(acc, 32);
    if (l < 16) yb[(size_t)t * DI + hh * 64 + p] = fmaf(Dph, xp, acc);
  }
}

__global__ __launch_bounds__(256) void scan_kernel(
    const float* __restrict__ rb, const float* __restrict__ kb,
    const float* __restrict__ vb, const float* __restrict__ db,
    const float* __restrict__ u, float* __restrict__ ob,
    const float* __restrict__ xbc, const float* __restrict__ dtb,
    const float* __restrict__ Alog, const float* __restrict__ Dpw,
    float* __restrict__ yb)
{
  __shared__ float smem[2 * 4 * 64 + 64];
  if (blockIdx.x < 6) rwkv_scan_body(blockIdx.x, threadIdx.x, rb, kb, vb, db, u, ob, smem);
  else mamba_scan_body(blockIdx.x - 6, threadIdx.x, xbc, dtb, Alog, Dpw, yb, smem);
}

// ---------------- RWKV groupnorm (per t,h over K) * silu(g) ----------------
__global__ __launch_bounds__(64) void gn_silu_kernel(const float* __restrict__ ob,
    const float* __restrict__ gbuf, const float* __restrict__ gnw,
    const float* __restrict__ gnb, float* __restrict__ out)
{
  int row = blockIdx.x;          // t*NH + h
  int t = row / NH, h = row % NH;
  int l = threadIdx.x;
  size_t ix = (size_t)t * DD + h * 64 + l;
  float v = ob[ix];
  float sum = v;
#pragma unroll
  for (int s = 1; s < 64; s <<= 1) sum += __shfl_xor(sum, s);
  float mu = sum * (1.f / 64.f);
  float d = v - mu;
  float vs = d * d;
#pragma unroll
  for (int s = 1; s < 64; s <<= 1) vs += __shfl_xor(vs, s);
  float var = vs * (1.f / 64.f);
  float nrm = d * rsqrtf(var + 1e-5f);
  float gv = gbuf[ix];
  out[ix] = fmaf(nrm, gnw[h * 64 + l], gnb[h * 64 + l]) * siluf(gv);
}

// ---------------- Mamba conv1d (+bias, silu) ----------------
__global__ void conv_kernel(const float* __restrict__ zx, const float* __restrict__ cw,
                            const float* __restrict__ cb, float* __restrict__ out)
{
  int idx = blockIdx.x * 256 + threadIdx.x;
  if (idx >= TT * CONVC) return;
  int t = idx / CONVC, c = idx % CONVC;
  float acc = cb[c];
#pragma unroll
  for (int j = 0; j < 4; ++j) {
    int tt = t + j - 3;
    if (tt >= 0) acc = fmaf(zx[(size_t)tt * XDIM + DI + c], cw[c * 4 + j], acc);
  }
  out[idx] = siluf(acc);
}

// ---------------- dt = softplus(raw + bias) ----------------
__global__ void dt_kernel(const float* __restrict__ zx, const float* __restrict__ dtb,
                          float* __restrict__ out)
{
  int idx = blockIdx.x * 256 + threadIdx.x;
  if (idx < TT * MH) {
    int t = idx / MH, hh = idx % MH;
    float v = zx[(size_t)t * XDIM + (XDIM - MH) + hh] + dtb[hh];
    out[idx] = (v > 20.f) ? v : log1pf(expf(v));
  }
}

// ---------------- Mamba out: rms(y * silu(z), mn_w) ----------------
__global__ __launch_bounds__(256) void mamba_norm_kernel(const float* __restrict__ yb,
    const float* __restrict__ zx, const float* __restrict__ mnw, float* __restrict__ out)
{
  int t = blockIdx.x;
  __shared__ float vbuf[DI];
  __shared__ float red[256];
  float ss = 0.f;
  for (int c = threadIdx.x; c < DI; c += 256) {
    float z = zx[(size_t)t * XDIM + c];
    float v = yb[(size_t)t * DI + c] * siluf(z);
    vbuf[c] = v;
    ss = fmaf(v, v, ss);
  }
  red[threadIdx.x] = ss; __syncthreads();
  for (int s = 128; s > 0; s >>= 1) {
    if (threadIdx.x < s) red[threadIdx.x] += red[threadIdx.x + s];
    __syncthreads();
  }
  float scale = rsqrtf(red[0] / DI + 1e-6f);
  for (int c = threadIdx.x; c < DI; c += 256)
    out[(size_t)t * DI + c] = vbuf[c] * scale * mnw[c];
}

// ---------------- gate = sigmoid([o_r,o_m]@gw + gb); h += gate*o_r + (1-gate)*o_m ----------------
__global__ __launch_bounds__(256) void gate_kernel(const float* __restrict__ orb,
    const float* __restrict__ omb, const float* __restrict__ gw,
    const float* __restrict__ gb, float* __restrict__ h)
{
  int t = blockIdx.x;
  float ss = 0.f;
  for (int c = threadIdx.x; c < DD; c += 256)
    ss += orb[(size_t)t * DD + c] * gw[c] + omb[(size_t)t * DD + c] * gw[DD + c];
  __shared__ float red[256];
  red[threadIdx.x] = ss; __syncthreads();
  for (int s = 128; s > 0; s >>= 1) {
    if (threadIdx.x < s) red[threadIdx.x] += red[threadIdx.x + s];
    __syncthreads();
  }
  float gate = sigmoidf_(red[0] + gb[0]);
  for (int c = threadIdx.x; c < DD; c += 256) {
    size_t ix = (size_t)t * DD + c;
    h[ix] += gate * orb[ix] + (1.f - gate) * omb[ix];
  }
}

// ---------------- gelu (exact) ----------------
__global__ void gelu_kernel(float* __restrict__ buf, int n)
{
  int idx = blockIdx.x * 256 + threadIdx.x;
  if (idx < n) {
    float x = buf[idx];
    buf[idx] = 0.5f * x * (1.f + erff(x * 0.70710678118654752440f));
  }
}

__global__ void add_kernel(float* __restrict__ h, const float* __restrict__ t, int n)
{
  int idx = blockIdx.x * 256 + threadIdx.x;
  if (idx < n) h[idx] += t[idx];
}

// ---------------- launcher ----------------
extern "C" void kernel_launch(void* const* d_in, const int* in_sizes, int n_in,
                              void* d_out, int out_size, void* d_ws, size_t ws_size,
                              hipStream_t stream)
{
  const int*   x        = (const int*)  d_in[0];
  const float* embed    = (const float*)d_in[1];
  const float* ln_w     = (const float*)d_in[2];
  const float* Wr       = (const float*)d_in[3];
  const float* Wk       = (const float*)d_in[4];
  const float* Wv       = (const float*)d_in[5];
  const float* Wg       = (const float*)d_in[6];
  const float* Ww       = (const float*)d_in[7];
  const float* w_bias   = (const float*)d_in[8];
  const float* u        = (const float*)d_in[9];
  const float* gn_w     = (const float*)d_in[10];
  const float* gn_b     = (const float*)d_in[11];
  const float* Wo       = (const float*)d_in[12];
  const float* W_in     = (const float*)d_in[13];
  const float* conv_w   = (const float*)d_in[14];
  const float* conv_b   = (const float*)d_in[15];
  const float* dt_bias  = (const float*)d_in[16];
  const float* A_log    = (const float*)d_in[17];
  const float* Dp       = (const float*)d_in[18];
  const float* mn_w     = (const float*)d_in[19];
  const float* W_out    = (const float*)d_in[20];
  const float* gw       = (const float*)d_in[21];
  const float* gb       = (const float*)d_in[22];
  const float* ffn_ln_w = (const float*)d_in[23];
  const float* ffn_w1   = (const float*)d_in[24];
  const float* ffn_w2   = (const float*)d_in[25];
  const float* ln_out_w = (const float*)d_in[26];

  float* ws = (float*)d_ws;
  size_t off = 0;
  auto alloc = [&](size_t n) { float* p = ws + off; off += n; return p; };
  float* h    = alloc((size_t)TT * DD);
  float* xn   = alloc((size_t)TT * DD);
  float* rb   = alloc((size_t)TT * DD);
  float* kb   = alloc((size_t)TT * DD);
  float* vb   = alloc((size_t)TT * DD);
  float* gbuf = alloc((size_t)TT * DD);
  float* db   = alloc((size_t)TT * DD);   // w -> decay (in place)
  float* so   = alloc((size_t)TT * DD);   // rwkv scan out
  float* go   = alloc((size_t)TT * DD);   // gn_silu out
  float* orb  = alloc((size_t)TT * DD);   // o_r
  float* omb  = alloc((size_t)TT * DD);   // o_m
  float* tmp  = alloc((size_t)TT * DD);
  float* zx   = alloc((size_t)TT * XDIM);
  float* xb   = alloc((size_t)TT * CONVC);
  float* dtb  = alloc((size_t)TT * MH);
  float* yb   = alloc((size_t)TT * DI);
  float* yn   = alloc((size_t)TT * DI);
  float* fh   = alloc((size_t)TT * 4 * DD);
  (void)ws_size; (void)in_sizes; (void)n_in; (void)out_size;

  dim3 blk(256);
  int gTD = (TT * DD + 255) / 256;

  embed_kernel<<<gTD, blk, 0, stream>>>(x, embed, h);

  for (int i = 0; i < NL; ++i) {
    const float* Wr_i = Wr + (size_t)i * DD * DD;
    const float* Wk_i = Wk + (size_t)i * DD * DD;
    const float* Wv_i = Wv + (size_t)i * DD * DD;
    const float* Wg_i = Wg + (size_t)i * DD * DD;
    const float* Ww_i = Ww + (size_t)i * DD * DD;
    const float* Wo_i = Wo + (size_t)i * DD * DD;
    const float* Win_i = W_in + (size_t)i * DD * XDIM;
    const float* Wout_i = W_out + (size_t)i * DI * DD;
    const float* f1_i = ffn_w1 + (size_t)i * DD * 4 * DD;
    const float* f2_i = ffn_w2 + (size_t)i * 4 * DD * DD;

    rms_kernel<<<TT, blk, 0, stream>>>(h, ln_w + (size_t)i * DD, xn, DD, 1e-6f);

    dim3 g384((DD + 63) / 64, TT / 64);
    gemm_kernel<0><<<g384, blk, 0, stream>>>(xn, Wr_i, rb, TT, DD, DD);
    gemm_kernel<0><<<g384, blk, 0, stream>>>(xn, Wk_i, kb, TT, DD, DD);
    gemm_kernel<0><<<g384, blk, 0, stream>>>(xn, Wv_i, vb, TT, DD, DD);
    gemm_kernel<0><<<g384, blk, 0, stream>>>(xn, Wg_i, gbuf, TT, DD, DD);
    gemm_kernel<0><<<g384, blk, 0, stream>>>(xn, Ww_i, db, TT, DD, DD);
    decay_kernel<<<gTD, blk, 0, stream>>>(db, w_bias + (size_t)i * DD);

    dim3 gzx((XDIM + 63) / 64, TT / 64);
    gemm_kernel<0><<<gzx, blk, 0, stream>>>(xn, Win_i, zx, TT, XDIM, DD);
    conv_kernel<<<(TT * CONVC + 255) / 256, blk, 0, stream>>>(
        zx, conv_w + (size_t)i * CONVC * 4, conv_b + (size_t)i * CONVC, xb);
    dt_kernel<<<(TT * MH + 255) / 256, blk, 0, stream>>>(zx, dt_bias + (size_t)i * MH, dtb);

    scan_kernel<<<18, blk, 0, stream>>>(rb, kb, vb, db, u + (size_t)i * NH * KK, so,
                                        xb, dtb, A_log + (size_t)i * MH, Dp + (size_t)i * MH, yb);

    gn_silu_kernel<<<TT * NH, dim3(64), 0, stream>>>(so, gbuf, gn_w + (size_t)i * DD,
                                                     gn_b + (size_t)i * DD, go);
    gemm_kernel<0><<<g384, blk, 0, stream>>>(go, Wo_i, orb, TT, DD, DD);

    mamba_norm_kernel<<<TT, blk, 0, stream>>>(yb, zx, mn_w + (size_t)i * DI, yn);
    gemm_kernel<0><<<g384, blk, 0, stream>>>(yn, Wout_i, omb, TT, DD, DI);

    gate_kernel<<<TT, blk, 0, stream>>>(orb, omb, gw + (size_t)i * 2 * DD, gb + i, h);

    rms_kernel<<<TT, blk, 0, stream>>>(h, ffn_ln_w + (size_t)i * DD, xn, DD, 1e-6f);
    dim3 gffn((4 * DD + 63) / 64, TT / 64);
    gemm_kernel<0><<<gffn, blk, 0, stream>>>(xn, f1_i, fh, TT, 4 * DD, DD);
    gelu_kernel<<<(TT * 4 * DD + 255) / 256, blk, 0, stream>>>(fh, TT * 4 * DD);
    gemm_kernel<0><<<g384, blk, 0, stream>>>(fh, f2_i, tmp, TT, DD, 4 * DD);
    add_kernel<<<gTD, blk, 0, stream>>>(h, tmp, TT * DD);
  }

  rms_kernel<<<TT, blk, 0, stream>>>(h, ln_out_w, xn, DD, 1e-6f);
  dim3 glog((NV + 63) / 64, TT / 64);
  gemm_kernel<1><<<glog, blk, 0, stream>>>(xn, embed, (float*)d_out, TT, NV, DD);
}

// Round 2
// 4430.790 us; speedup vs baseline: 1.6749x; 1.6749x over previous
//
#include <hip/hip_runtime.h>
#include <math.h>

#define TT 1024
#define DD 384
#define NH 6
#define DI 768
#define MH 12
#define DS 64
#define NL 8
#define XDIM 1676   // 2*DI + 2*DS + MH
#define CONVC 896   // DI + 2*DS
#define NV 32000
#define PW 1920     // fused projection width: [r|k|v|g|w] * 384

typedef __attribute__((ext_vector_type(8))) short short8;
typedef __attribute__((ext_vector_type(4))) float f32x4;

// ---------------- helpers ----------------
__device__ __forceinline__ float siluf(float x) { return x / (1.f + expf(-x)); }
__device__ __forceinline__ float sigmoidf_(float x) { return 1.f / (1.f + expf(-x)); }
__device__ __forceinline__ unsigned short f2b(float x) {
  union { float f; unsigned int u; } v; v.f = x;
  unsigned int r = v.u + 0x7fffu + ((v.u >> 16) & 1u);
  return (unsigned short)(r >> 16);
}

// ---------------- bf16 MFMA GEMM: C[1024,N] = A[1024,K]bf16 @ Bt[N,K]bf16^T ----------------
// 64x64 tile, 4 waves, each wave a 32x32 sub-tile (2x2 MFMA 16x16x32 frags).
// LDS staging via global_load_lds(16B), source pre-swizzled chunk^= (row>>1)&3.
__global__ __launch_bounds__(256) void gemm_bf16(
    const unsigned short* __restrict__ A, const unsigned short* __restrict__ Bt,
    float* __restrict__ C, int N, int K, int ldC)
{
  __shared__ unsigned short As[2048];   // [64][32]
  __shared__ unsigned short Bs[2048];   // [64][32]
  int tid = threadIdx.x;
  int wid = tid >> 6, lane = tid & 63;
  int m0 = blockIdx.y * 64, n0 = blockIdx.x * 64;
  int wr = wid >> 1, wc = wid & 1;
  // staging: thread t -> LDS row sr=t>>2, phys 16B-chunk t&3; source chunk = phys ^ f(sr)
  int sr = tid >> 2;
  int scs = ((tid & 3) ^ ((sr >> 1) & 3)) * 8;
  const unsigned short* ga = A  + (size_t)(m0 + sr) * K + scs;
  const unsigned short* gb = Bt + (size_t)(n0 + sr) * K + scs;
  unsigned short* la = As + wid * 512;   // wave-uniform LDS base (64 lanes * 8 elem)
  unsigned short* lb = Bs + wid * 512;
  int fr = lane & 15, fc = lane >> 4;
  f32x4 zz = {0.f, 0.f, 0.f, 0.f};
  f32x4 acc[2][2];
  acc[0][0] = zz; acc[0][1] = zz; acc[1][0] = zz; acc[1][1] = zz;

  for (int k0 = 0; k0 < K; k0 += 32) {
    __builtin_amdgcn_global_load_lds((const __attribute__((address_space(1))) void*)(ga + k0),
                                     (__attribute__((address_space(3))) void*)la, 16, 0, 0);
    __builtin_amdgcn_global_load_lds((const __attribute__((address_space(1))) void*)(gb + k0),
                                     (__attribute__((address_space(3))) void*)lb, 16, 0, 0);
    __syncthreads();
    short8 af[2], bf[2];
#pragma unroll
    for (int mg = 0; mg < 2; ++mg) {
      int ar = wr * 32 + mg * 16 + fr;
      af[mg] = *reinterpret_cast<const short8*>(&As[ar * 32 + ((fc ^ ((ar >> 1) & 3)) * 8)]);
    }
#pragma unroll
    for (int ng = 0; ng < 2; ++ng) {
      int br = wc * 32 + ng * 16 + fr;
      bf[ng] = *reinterpret_cast<const short8*>(&Bs[br * 32 + ((fc ^ ((br >> 1) & 3)) * 8)]);
    }
#pragma unroll
    for (int mg = 0; mg < 2; ++mg)
#pragma unroll
      for (int ng = 0; ng < 2; ++ng)
        acc[mg][ng] = __builtin_amdgcn_mfma_f32_16x16x32_bf16(af[mg], bf[ng], acc[mg][ng], 0, 0, 0);
    __syncthreads();
  }
#pragma unroll
  for (int mg = 0; mg < 2; ++mg)
#pragma unroll
    for (int ng = 0; ng < 2; ++ng) {
      int col = n0 + wc * 32 + ng * 16 + fr;
      if (col < N) {
#pragma unroll
        for (int j = 0; j < 4; ++j) {
          int row = m0 + wr * 32 + mg * 16 + fc * 4 + j;
          C[(size_t)row * ldC + col] = acc[mg][ng][j];
        }
      }
    }
}

// ---------------- weight transpose + fp32->bf16: dst[n][k] = src[k][n] ----------------
__global__ __launch_bounds__(256) void transconv_kernel(
    const float* __restrict__ src, unsigned short* __restrict__ dst,
    int K, int N, int Npad, size_t srcStride, size_t dstStride)
{
  __shared__ float tile[32][33];
  src += (size_t)blockIdx.z * srcStride;
  dst += (size_t)blockIdx.z * dstStride;
  int k0 = blockIdx.y * 32, n0 = blockIdx.x * 32;
  int tx = threadIdx.x & 31, ty = threadIdx.x >> 5;
  for (int i = ty; i < 32; i += 8) {
    int k = k0 + i, n = n0 + tx;
    tile[i][tx] = (k < K && n < N) ? src[(size_t)k * N + n] : 0.f;
  }
  __syncthreads();
  for (int i = ty; i < 32; i += 8) {
    int n = n0 + i, k = k0 + tx;
    if (n < Npad && k < K) dst[(size_t)n * K + k] = f2b(tile[tx][i]);
  }
}

__global__ void conv_b16_kernel(const float* __restrict__ src, unsigned short* __restrict__ dst, int n)
{
  int idx = blockIdx.x * 256 + threadIdx.x;
  if (idx < n) dst[idx] = f2b(src[idx]);
}

// ---------------- embedding gather ----------------
__global__ void embed_kernel(const int* __restrict__ x, const float* __restrict__ embed,
                             float* __restrict__ h)
{
  int idx = blockIdx.x * 256 + threadIdx.x;
  if (idx < TT * DD) {
    int t = idx / DD, d = idx % DD;
    h[idx] = embed[(size_t)x[t] * DD + d];
  }
}

// ---------------- RMSNorm -> bf16 out ----------------
__global__ __launch_bounds__(256) void rms_kernel(const float* __restrict__ in,
                                                  const float* __restrict__ w,
                                                  unsigned short* __restrict__ out,
                                                  int ncol, float eps)
{
  int t = blockIdx.x;
  const float* row = in + (size_t)t * ncol;
  float ss = 0.f;
  for (int c = threadIdx.x; c < ncol; c += 256) { float v = row[c]; ss = fmaf(v, v, ss); }
  __shared__ float red[256];
  red[threadIdx.x] = ss; __syncthreads();
  for (int s = 128; s > 0; s >>= 1) {
    if (threadIdx.x < s) red[threadIdx.x] += red[threadIdx.x + s];
    __syncthreads();
  }
  float scale = rsqrtf(red[0] / ncol + eps);
  for (int c = threadIdx.x; c < ncol; c += 256) out[(size_t)t * ncol + c] = f2b(w[c] * row[c] * scale);
}

// ---------------- RWKV decay in fused proj buffer ----------------
__global__ void decay_kernel(float* __restrict__ P, const float* __restrict__ wb)
{
  int idx = blockIdx.x * 256 + threadIdx.x;
  if (idx < TT * DD) {
    int t = idx / DD, d = idx % DD;
    size_t ix = (size_t)t * PW + 1536 + d;
    P[ix] = expf(-expf(P[ix] + wb[d]));
  }
}

// ---------------- fused sequential scans ----------------
__device__ __forceinline__ void rwkv_scan_body(int h, int tid,
    const float* __restrict__ P, const float* __restrict__ u,
    float* __restrict__ ob, float* smem)
{
  float* sbuf = smem;          // [2][4][64]
  float* us = smem + 512;      // [64]
  if (tid < 64) us[tid] = u[h * 64 + tid];
  int wv = tid >> 6, l = tid & 63;
  int vv = wv * 16 + (l & 15);
  int kc = l >> 4;
  int arr = tid >> 6, idx = tid & 63;
  int off = (arr == 0) ? 0 : (arr == 1) ? 384 : (arr == 2) ? 1536 : 768;  // r,k,decay,v
  size_t base = (size_t)h * 64 + idx + off;
  float S[16];
#pragma unroll
  for (int i = 0; i < 16; i++) S[i] = 0.f;
  float reg = P[base];
  for (int t = 0; t < TT; ++t) {
    float* cb = sbuf + (t & 1) * 256;
    cb[arr * 64 + idx] = reg;
    if (t + 1 < TT) reg = P[(size_t)(t + 1) * PW + base];
    __syncthreads();
    float vt = cb[192 + vv];
    float acc = 0.f;
#pragma unroll
    for (int i = 0; i < 16; ++i) {
      int kkk = kc * 16 + i;
      float kv_ = cb[64 + kkk] * vt;
      acc = fmaf(cb[kkk], fmaf(us[kkk], kv_, S[i]), acc);
      S[i] = fmaf(cb[128 + kkk], S[i], kv_);
    }
    acc += __shfl_xor(acc, 16);
    acc += __shfl_xor(acc, 32);
    if (l < 16) ob[(size_t)t * DD + h * 64 + vv] = acc;
  }
}

__device__ __forceinline__ void mamba_scan_body(int hh, int tid,
    const float* __restrict__ xbc, const float* __restrict__ dtb,
    const float* __restrict__ Alog, const float* __restrict__ Dpw,
    float* __restrict__ yb, float* smem)
{
  float* sbuf = smem;
  int wv = tid >> 6, l = tid & 63;
  int p = wv * 16 + (l & 15);
  int sc = l >> 4;
  int arr = tid >> 6, idx = tid & 63;
  float A = -expf(Alog[hh]);
  float Dph = Dpw[hh];
  int off = (arr == 0) ? (hh * 64 + idx) : (arr == 1) ? (DI + idx) : (DI + DS + idx);
  float S[16];
#pragma unroll
  for (int i = 0; i < 16; i++) S[i] = 0.f;
  float reg = (arr < 3) ? xbc[off] : dtb[hh];
  for (int t = 0; t < TT; ++t) {
    float* cb = sbuf + (t & 1) * 256;
    if (arr < 3) cb[arr * 64 + idx] = reg;
    else if (idx == 0) cb[192] = reg;
    if (t + 1 < TT) reg = (arr < 3) ? xbc[(size_t)(t + 1) * CONVC + off]
                                    : dtb[(size_t)(t + 1) * MH + hh];
    __syncthreads();
    float dt_ = cb[192];
    float dA = expf(dt_ * A);
    float xp = cb[p];
    float dtx = dt_ * xp;
    float acc = 0.f;
#pragma unroll
    for (int i = 0; i < 16; ++i) {
      int s = sc * 16 + i;
      S[i] = fmaf(dA, S[i], dtx * cb[64 + s]);
      acc = fmaf(S[i], cb[128 + s], acc);
    }
    acc += __shfl_xor(acc, 16);
    acc += __shfl_xor(acc, 32);
    if (l < 16) yb[(size_t)t * DI + hh * 64 + p] = fmaf(Dph, xp, acc);
  }
}

__global__ __launch_bounds__(256) void scan_kernel(
    const float* __restrict__ P, const float* __restrict__ u, float* __restrict__ ob,
    const float* __restrict__ xbc, const float* __restrict__ dtb,
    const float* __restrict__ Alog, const float* __restrict__ Dpw,
    float* __restrict__ yb)
{
  __shared__ float smem[2 * 4 * 64 + 64];
  if (blockIdx.x < 6) rwkv_scan_body(blockIdx.x, threadIdx.x, P, u, ob, smem);
  else mamba_scan_body(blockIdx.x - 6, threadIdx.x, xbc, dtb, Alog, Dpw, yb, smem);
}

// ---------------- RWKV groupnorm * silu(g) -> bf16 ----------------
__global__ __launch_bounds__(64) void gn_silu_kernel(const float* __restrict__ ob,
    const float* __restrict__ P, const float* __restrict__ gnw,
    const float* __restrict__ gnb, unsigned short* __restrict__ out)
{
  int row = blockIdx.x;          // t*NH + h
  int t = row / NH, h = row % NH;
  int l = threadIdx.x;
  size_t ix = (size_t)t * DD + h * 64 + l;
  float v = ob[ix];
  float sum = v;
#pragma unroll
  for (int s = 1; s < 64; s <<= 1) sum += __shfl_xor(sum, s);
  float mu = sum * (1.f / 64.f);
  float d = v - mu;
  float vs = d * d;
#pragma unroll
  for (int s = 1; s < 64; s <<= 1) vs += __shfl_xor(vs, s);
  float var = vs * (1.f / 64.f);
  float nrm = d * rsqrtf(var + 1e-5f);
  float gv = P[(size_t)t * PW + 1152 + h * 64 + l];
  out[ix] = f2b(fmaf(nrm, gnw[h * 64 + l], gnb[h * 64 + l]) * siluf(gv));
}

// ---------------- Mamba conv1d (+bias, silu) ----------------
__global__ void conv_kernel(const float* __restrict__ zx, const float* __restrict__ cw,
                            const float* __restrict__ cb, float* __restrict__ out)
{
  int idx = blockIdx.x * 256 + threadIdx.x;
  if (idx >= TT * CONVC) return;
  int t = idx / CONVC, c = idx % CONVC;
  float acc = cb[c];
#pragma unroll
  for (int j = 0; j < 4; ++j) {
    int tt = t + j - 3;
    if (tt >= 0) acc = fmaf(zx[(size_t)tt * XDIM + DI + c], cw[c * 4 + j], acc);
  }
  out[idx] = siluf(acc);
}

// ---------------- dt = softplus(raw + bias) ----------------
__global__ void dt_kernel(const float* __restrict__ zx, const float* __restrict__ dtb,
                          float* __restrict__ out)
{
  int idx = blockIdx.x * 256 + threadIdx.x;
  if (idx < TT * MH) {
    int t = idx / MH, hh = idx % MH;
    float v = zx[(size_t)t * XDIM + (XDIM - MH) + hh] + dtb[hh];
    out[idx] = (v > 20.f) ? v : log1pf(expf(v));
  }
}

// ---------------- Mamba out: rms(y * silu(z), mn_w) -> bf16 ----------------
__global__ __launch_bounds__(256) void mamba_norm_kernel(const float* __restrict__ yb,
    const float* __restrict__ zx, const float* __restrict__ mnw, unsigned short* __restrict__ out)
{
  int t = blockIdx.x;
  __shared__ float vbuf[DI];
  __shared__ float red[256];
  float ss = 0.f;
  for (int c = threadIdx.x; c < DI; c += 256) {
    float z = zx[(size_t)t * XDIM + c];
    float v = yb[(size_t)t * DI + c] * siluf(z);
    vbuf[c] = v;
    ss = fmaf(v, v, ss);
  }
  red[threadIdx.x] = ss; __syncthreads();
  for (int s = 128; s > 0; s >>= 1) {
    if (threadIdx.x < s) red[threadIdx.x] += red[threadIdx.x + s];
    __syncthreads();
  }
  float scale = rsqrtf(red[0] / DI + 1e-6f);
  for (int c = threadIdx.x; c < DI; c += 256)
    out[(size_t)t * DI + c] = f2b(vbuf[c] * scale * mnw[c]);
}

// ---------------- gate combine ----------------
__global__ __launch_bounds__(256) void gate_kernel(const float* __restrict__ orb,
    const float* __restrict__ omb, const float* __restrict__ gw,
    const float* __restrict__ gb, float* __restrict__ h)
{
  int t = blockIdx.x;
  float ss = 0.f;
  for (int c = threadIdx.x; c < DD; c += 256)
    ss += orb[(size_t)t * DD + c] * gw[c] + omb[(size_t)t * DD + c] * gw[DD + c];
  __shared__ float red[256];
  red[threadIdx.x] = ss; __syncthreads();
  for (int s = 128; s > 0; s >>= 1) {
    if (threadIdx.x < s) red[threadIdx.x] += red[threadIdx.x + s];
    __syncthreads();
  }
  float gate = sigmoidf_(red[0] + gb[0]);
  for (int c = threadIdx.x; c < DD; c += 256) {
    size_t ix = (size_t)t * DD + c;
    h[ix] += gate * orb[ix] + (1.f - gate) * omb[ix];
  }
}

// ---------------- gelu (exact) fp32 -> bf16 ----------------
__global__ void gelu_kernel(const float* __restrict__ in, unsigned short* __restrict__ out, int n)
{
  int idx = blockIdx.x * 256 + threadIdx.x;
  if (idx < n) {
    float x = in[idx];
    out[idx] = f2b(0.5f * x * (1.f + erff(x * 0.70710678118654752440f)));
  }
}

__global__ void add_kernel(float* __restrict__ h, const float* __restrict__ t, int n)
{
  int idx = blockIdx.x * 256 + threadIdx.x;
  if (idx < n) h[idx] += t[idx];
}

// ---------------- launcher ----------------
extern "C" void kernel_launch(void* const* d_in, const int* in_sizes, int n_in,
                              void* d_out, int out_size, void* d_ws, size_t ws_size,
                              hipStream_t stream)
{
  const int*   x        = (const int*)  d_in[0];
  const float* embed    = (const float*)d_in[1];
  const float* ln_w     = (const float*)d_in[2];
  const float* Wr       = (const float*)d_in[3];
  const float* Wk       = (const float*)d_in[4];
  const float* Wv       = (const float*)d_in[5];
  const float* Wg       = (const float*)d_in[6];
  const float* Ww       = (const float*)d_in[7];
  const float* w_bias   = (const float*)d_in[8];
  const float* u        = (const float*)d_in[9];
  const float* gn_w     = (const float*)d_in[10];
  const float* gn_b     = (const float*)d_in[11];
  const float* Wo       = (const float*)d_in[12];
  const float* W_in     = (const float*)d_in[13];
  const float* conv_w   = (const float*)d_in[14];
  const float* conv_b   = (const float*)d_in[15];
  const float* dt_bias  = (const float*)d_in[16];
  const float* A_log    = (const float*)d_in[17];
  const float* Dp       = (const float*)d_in[18];
  const float* mn_w     = (const float*)d_in[19];
  const float* W_out    = (const float*)d_in[20];
  const float* gw       = (const float*)d_in[21];
  const float* gb       = (const float*)d_in[22];
  const float* ffn_ln_w = (const float*)d_in[23];
  const float* ffn_w1   = (const float*)d_in[24];
  const float* ffn_w2   = (const float*)d_in[25];
  const float* ln_out_w = (const float*)d_in[26];

  char* base = (char*)d_ws;
  size_t off = 0;
  auto alloc = [&](size_t bytes) { off = (off + 255) & ~(size_t)255; void* p = base + off; off += bytes; return p; };

  float* h    = (float*)alloc((size_t)TT * DD * 4);
  float* P    = (float*)alloc((size_t)TT * PW * 4);
  float* zx   = (float*)alloc((size_t)TT * XDIM * 4);
  float* xb   = (float*)alloc((size_t)TT * CONVC * 4);
  float* dtb  = (float*)alloc((size_t)TT * MH * 4);
  float* yb   = (float*)alloc((size_t)TT * DI * 4);
  float* so   = (float*)alloc((size_t)TT * DD * 4);
  float* orb  = (float*)alloc((size_t)TT * DD * 4);
  float* omb  = (float*)alloc((size_t)TT * DD * 4);
  float* tmp  = (float*)alloc((size_t)TT * DD * 4);
  float* fh   = (float*)alloc((size_t)TT * 1536 * 4);
  unsigned short* xnb = (unsigned short*)alloc((size_t)TT * DD * 2);
  unsigned short* gob = (unsigned short*)alloc((size_t)TT * DD * 2);
  unsigned short* ynb = (unsigned short*)alloc((size_t)TT * DI * 2);
  unsigned short* fhb = (unsigned short*)alloc((size_t)TT * 1536 * 2);
  unsigned short* WcatT = (unsigned short*)alloc((size_t)NL * PW * 384 * 2);
  unsigned short* WinT  = (unsigned short*)alloc((size_t)NL * 1728 * 384 * 2);
  unsigned short* WoT   = (unsigned short*)alloc((size_t)NL * 384 * 384 * 2);
  unsigned short* WoutT = (unsigned short*)alloc((size_t)NL * 384 * 768 * 2);
  unsigned short* F1T   = (unsigned short*)alloc((size_t)NL * 1536 * 384 * 2);
  unsigned short* F2T   = (unsigned short*)alloc((size_t)NL * 384 * 1536 * 2);
  unsigned short* embB  = (unsigned short*)alloc((size_t)NV * DD * 2);
  (void)ws_size; (void)in_sizes; (void)n_in; (void)out_size;

  dim3 blk(256);
  int gTD = (TT * DD + 255) / 256;

  // ---- one-time (per launch) weight conversion ----
  const float* Wrkvgw[5] = {Wr, Wk, Wv, Wg, Ww};
  for (int j = 0; j < 5; ++j)
    transconv_kernel<<<dim3(12, 12, 8), blk, 0, stream>>>(
        Wrkvgw[j], WcatT + (size_t)j * 384 * 384, 384, 384, 384,
        (size_t)384 * 384, (size_t)PW * 384);
  transconv_kernel<<<dim3(54, 12, 8), blk, 0, stream>>>(
      W_in, WinT, 384, XDIM, 1728, (size_t)384 * XDIM, (size_t)1728 * 384);
  transconv_kernel<<<dim3(12, 12, 8), blk, 0, stream>>>(
      Wo, WoT, 384, 384, 384, (size_t)384 * 384, (size_t)384 * 384);
  transconv_kernel<<<dim3(12, 24, 8), blk, 0, stream>>>(
      W_out, WoutT, 768, 384, 384, (size_t)768 * 384, (size_t)384 * 768);
  transconv_kernel<<<dim3(48, 12, 8), blk, 0, stream>>>(
      ffn_w1, F1T, 384, 1536, 1536, (size_t)384 * 1536, (size_t)1536 * 384);
  transconv_kernel<<<dim3(12, 48, 8), blk, 0, stream>>>(
      ffn_w2, F2T, 1536, 384, 384, (size_t)1536 * 384, (size_t)384 * 1536);
  conv_b16_kernel<<<(NV * DD + 255) / 256, blk, 0, stream>>>(embed, embB, NV * DD);

  embed_kernel<<<gTD, blk, 0, stream>>>(x, embed, h);

  for (int i = 0; i < NL; ++i) {
    rms_kernel<<<TT, blk, 0, stream>>>(h, ln_w + (size_t)i * DD, xnb, DD, 1e-6f);

    gemm_bf16<<<dim3(30, 16), blk, 0, stream>>>(
        xnb, WcatT + (size_t)i * PW * 384, P, PW, 384, PW);
    decay_kernel<<<gTD, blk, 0, stream>>>(P, w_bias + (size_t)i * DD);

    gemm_bf16<<<dim3(27, 16), blk, 0, stream>>>(
        xnb, WinT + (size_t)i * 1728 * 384, zx, XDIM, 384, XDIM);
    conv_kernel<<<(TT * CONVC + 255) / 256, blk, 0, stream>>>(
        zx, conv_w + (size_t)i * CONVC * 4, conv_b + (size_t)i * CONVC, xb);
    dt_kernel<<<(TT * MH + 255) / 256, blk, 0, stream>>>(zx, dt_bias + (size_t)i * MH, dtb);

    scan_kernel<<<18, blk, 0, stream>>>(P, u + (size_t)i * NH * 64, so,
                                        xb, dtb, A_log + (size_t)i * MH, Dp + (size_t)i * MH, yb);

    gn_silu_kernel<<<TT * NH, dim3(64), 0, stream>>>(so, P, gn_w + (size_t)i * DD,
                                                     gn_b + (size_t)i * DD, gob);
    gemm_bf16<<<dim3(6, 16), blk, 0, stream>>>(
        gob, WoT + (size_t)i * 384 * 384, orb, DD, 384, DD);

    mamba_norm_kernel<<<TT, blk, 0, stream>>>(yb, zx, mn_w + (size_t)i * DI, ynb);
    gemm_bf16<<<dim3(6, 16), blk, 0, stream>>>(
        ynb, WoutT + (size_t)i * 384 * 768, omb, DD, 768, DD);

    gate_kernel<<<TT, blk, 0, stream>>>(orb, omb, gw + (size_t)i * 2 * DD, gb + i, h);

    rms_kernel<<<TT, blk, 0, stream>>>(h, ffn_ln_w + (size_t)i * DD, xnb, DD, 1e-6f);
    gemm_bf16<<<dim3(24, 16), blk, 0, stream>>>(
        xnb, F1T + (size_t)i * 1536 * 384, fh, 1536, 384, 1536);
    gelu_kernel<<<(TT * 1536 + 255) / 256, blk, 0, stream>>>(fh, fhb, TT * 1536);
    gemm_bf16<<<dim3(6, 16), blk, 0, stream>>>(
        fhb, F2T + (size_t)i * 384 * 1536, tmp, DD, 1536, DD);
    add_kernel<<<gTD, blk, 0, stream>>>(h, tmp, TT * DD);
  }

  rms_kernel<<<TT, blk, 0, stream>>>(h, ln_out_w, xnb, DD, 1e-6f);
  gemm_bf16<<<dim3(500, 16), blk, 0, stream>>>(
      xnb, embB, (float*)d_out, NV, 384, NV);
}

// Round 3
// 1489.654 us; speedup vs baseline: 4.9818x; 2.9744x over previous
//
#include <hip/hip_runtime.h>
#include <math.h>

#define TT 1024
#define DD 384
#define NH 6
#define DI 768
#define MH 12
#define DS 64
#define NL 8
#define XDIM 1676   // 2*DI + 2*DS + MH
#define CONVC 896   // DI + 2*DS
#define NV 32000
#define PW 1920     // fused projection width: [r|k|v|g|w] * 384
#define CHK 64      // scan chunk length
#define NCH 16      // number of chunks

typedef __attribute__((ext_vector_type(8))) short short8;
typedef __attribute__((ext_vector_type(4))) float f32x4;

// ---------------- helpers ----------------
__device__ __forceinline__ float siluf(float x) { return x / (1.f + expf(-x)); }
__device__ __forceinline__ float sigmoidf_(float x) { return 1.f / (1.f + expf(-x)); }
__device__ __forceinline__ unsigned short f2b(float x) {
  union { float f; unsigned int u; } v; v.f = x;
  unsigned int r = v.u + 0x7fffu + ((v.u >> 16) & 1u);
  return (unsigned short)(r >> 16);
}

// ---------------- bf16 MFMA GEMM: C[1024,N] = A[1024,K]bf16 @ Bt[N,K]bf16^T ----------------
__global__ __launch_bounds__(256) void gemm_bf16(
    const unsigned short* __restrict__ A, const unsigned short* __restrict__ Bt,
    float* __restrict__ C, int N, int K, int ldC)
{
  __shared__ unsigned short As[2048];   // [64][32]
  __shared__ unsigned short Bs[2048];   // [64][32]
  int tid = threadIdx.x;
  int wid = tid >> 6, lane = tid & 63;
  int m0 = blockIdx.y * 64, n0 = blockIdx.x * 64;
  int wr = wid >> 1, wc = wid & 1;
  int sr = tid >> 2;
  int scs = ((tid & 3) ^ ((sr >> 1) & 3)) * 8;
  const unsigned short* ga = A  + (size_t)(m0 + sr) * K + scs;
  const unsigned short* gb = Bt + (size_t)(n0 + sr) * K + scs;
  unsigned short* la = As + wid * 512;
  unsigned short* lb = Bs + wid * 512;
  int fr = lane & 15, fc = lane >> 4;
  f32x4 zz = {0.f, 0.f, 0.f, 0.f};
  f32x4 acc[2][2];
  acc[0][0] = zz; acc[0][1] = zz; acc[1][0] = zz; acc[1][1] = zz;

  for (int k0 = 0; k0 < K; k0 += 32) {
    __builtin_amdgcn_global_load_lds((const __attribute__((address_space(1))) void*)(ga + k0),
                                     (__attribute__((address_space(3))) void*)la, 16, 0, 0);
    __builtin_amdgcn_global_load_lds((const __attribute__((address_space(1))) void*)(gb + k0),
                                     (__attribute__((address_space(3))) void*)lb, 16, 0, 0);
    __syncthreads();
    short8 af[2], bf[2];
#pragma unroll
    for (int mg = 0; mg < 2; ++mg) {
      int ar = wr * 32 + mg * 16 + fr;
      af[mg] = *reinterpret_cast<const short8*>(&As[ar * 32 + ((fc ^ ((ar >> 1) & 3)) * 8)]);
    }
#pragma unroll
    for (int ng = 0; ng < 2; ++ng) {
      int br = wc * 32 + ng * 16 + fr;
      bf[ng] = *reinterpret_cast<const short8*>(&Bs[br * 32 + ((fc ^ ((br >> 1) & 3)) * 8)]);
    }
#pragma unroll
    for (int mg = 0; mg < 2; ++mg)
#pragma unroll
      for (int ng = 0; ng < 2; ++ng)
        acc[mg][ng] = __builtin_amdgcn_mfma_f32_16x16x32_bf16(af[mg], bf[ng], acc[mg][ng], 0, 0, 0);
    __syncthreads();
  }
#pragma unroll
  for (int mg = 0; mg < 2; ++mg)
#pragma unroll
    for (int ng = 0; ng < 2; ++ng) {
      int col = n0 + wc * 32 + ng * 16 + fr;
      if (col < N) {
#pragma unroll
        for (int j = 0; j < 4; ++j) {
          int row = m0 + wr * 32 + mg * 16 + fc * 4 + j;
          C[(size_t)row * ldC + col] = acc[mg][ng][j];
        }
      }
    }
}

// ---------------- weight transpose + fp32->bf16 ----------------
__global__ __launch_bounds__(256) void transconv_kernel(
    const float* __restrict__ src, unsigned short* __restrict__ dst,
    int K, int N, int Npad, size_t srcStride, size_t dstStride)
{
  __shared__ float tile[32][33];
  src += (size_t)blockIdx.z * srcStride;
  dst += (size_t)blockIdx.z * dstStride;
  int k0 = blockIdx.y * 32, n0 = blockIdx.x * 32;
  int tx = threadIdx.x & 31, ty = threadIdx.x >> 5;
  for (int i = ty; i < 32; i += 8) {
    int k = k0 + i, n = n0 + tx;
    tile[i][tx] = (k < K && n < N) ? src[(size_t)k * N + n] : 0.f;
  }
  __syncthreads();
  for (int i = ty; i < 32; i += 8) {
    int n = n0 + i, k = k0 + tx;
    if (n < Npad && k < K) dst[(size_t)n * K + k] = f2b(tile[tx][i]);
  }
}

__global__ void conv_b16_kernel(const float* __restrict__ src, unsigned short* __restrict__ dst, int n)
{
  int idx = blockIdx.x * 256 + threadIdx.x;
  if (idx < n) dst[idx] = f2b(src[idx]);
}

// ---------------- embedding gather ----------------
__global__ void embed_kernel(const int* __restrict__ x, const float* __restrict__ embed,
                             float* __restrict__ h)
{
  int idx = blockIdx.x * 256 + threadIdx.x;
  if (idx < TT * DD) {
    int t = idx / DD, d = idx % DD;
    h[idx] = embed[(size_t)x[t] * DD + d];
  }
}

// ---------------- RMSNorm -> bf16 out ----------------
__global__ __launch_bounds__(256) void rms_kernel(const float* __restrict__ in,
                                                  const float* __restrict__ w,
                                                  unsigned short* __restrict__ out,
                                                  int ncol, float eps)
{
  int t = blockIdx.x;
  const float* row = in + (size_t)t * ncol;
  float ss = 0.f;
  for (int c = threadIdx.x; c < ncol; c += 256) { float v = row[c]; ss = fmaf(v, v, ss); }
  __shared__ float red[256];
  red[threadIdx.x] = ss; __syncthreads();
  for (int s = 128; s > 0; s >>= 1) {
    if (threadIdx.x < s) red[threadIdx.x] += red[threadIdx.x + s];
    __syncthreads();
  }
  float scale = rsqrtf(red[0] / ncol + eps);
  for (int c = threadIdx.x; c < ncol; c += 256) out[(size_t)t * ncol + c] = f2b(w[c] * row[c] * scale);
}

// ---------------- RWKV decay in fused proj buffer ----------------
__global__ void decay_kernel(float* __restrict__ P, const float* __restrict__ wb)
{
  int idx = blockIdx.x * 256 + threadIdx.x;
  if (idx < TT * DD) {
    int t = idx / DD, d = idx % DD;
    size_t ix = (size_t)t * PW + 1536 + d;
    P[ix] = expf(-expf(P[ix] + wb[d]));
  }
}

// ---------------- Phase A: per-chunk local scans ----------------
// blocks 0..95: RWKV (h = b>>4, chunk c = b&15); 96..287: Mamba (hh, c)
__global__ __launch_bounds__(256) void scanA_kernel(
    const float* __restrict__ P, const float* __restrict__ u,
    float* __restrict__ so, float* __restrict__ rPb,
    float* __restrict__ MstR, float* __restrict__ DcR,
    const float* __restrict__ xbc, const float* __restrict__ dtb,
    const float* __restrict__ Alog, const float* __restrict__ Dpw,
    float* __restrict__ yb, float* __restrict__ Ccb,
    float* __restrict__ MstM, float* __restrict__ DcM)
{
  __shared__ float smem[2 * 256 + 64];
  int b = blockIdx.x, tid = threadIdx.x;
  if (b < 96) {
    int h = b >> 4, c = b & 15;
    float* sbuf = smem; float* us = smem + 512;
    if (tid < 64) us[tid] = u[h * 64 + tid];
    int wv = tid >> 6, l = tid & 63;
    int vv = wv * 16 + (l & 15);
    int kc = l >> 4;
    int arr = tid >> 6, idx = tid & 63;
    int off = (arr == 0) ? 0 : (arr == 1) ? 384 : (arr == 2) ? 1536 : 768;  // r,k,decay,v
    size_t base = (size_t)h * 64 + idx + off;
    int t0 = c * CHK;
    float S[16], Pc[16];
#pragma unroll
    for (int i = 0; i < 16; i++) { S[i] = 0.f; Pc[i] = 1.f; }
    float reg = P[(size_t)t0 * PW + base];
    bool st = (wv == 0) && ((l & 15) == 0);   // 4 threads, kc = 0..3
    for (int t = 0; t < CHK; ++t) {
      int tt = t0 + t;
      float* cb = sbuf + (t & 1) * 256;
      cb[arr * 64 + idx] = reg;
      if (t + 1 < CHK) reg = P[(size_t)(tt + 1) * PW + base];
      __syncthreads();
      float vt = cb[192 + vv];
      float acc = 0.f;
      float rp[16];
#pragma unroll
      for (int i = 0; i < 16; ++i) {
        int kk = kc * 16 + i;
        float rv = cb[kk], kv = cb[64 + kk], dv = cb[128 + kk];
        rp[i] = rv * Pc[i];
        float kvv = kv * vt;
        acc = fmaf(rv, fmaf(us[kk], kvv, S[i]), acc);
        S[i] = fmaf(dv, S[i], kvv);
        Pc[i] *= dv;
      }
      acc += __shfl_xor(acc, 16);
      acc += __shfl_xor(acc, 32);
      if (l < 16) so[(size_t)tt * DD + h * 64 + vv] = acc;
      if (st) {
        float4* dst = (float4*)&rPb[(size_t)tt * DD + h * 64 + kc * 16];
        dst[0] = make_float4(rp[0], rp[1], rp[2], rp[3]);
        dst[1] = make_float4(rp[4], rp[5], rp[6], rp[7]);
        dst[2] = make_float4(rp[8], rp[9], rp[10], rp[11]);
        dst[3] = make_float4(rp[12], rp[13], rp[14], rp[15]);
      }
    }
    // final local state, v-major: Mst[h][c][v][k]
    float* ms = MstR + (size_t)(h * NCH + c) * 4096;
    float4* msv = (float4*)&ms[vv * 64 + kc * 16];
    msv[0] = make_float4(S[0], S[1], S[2], S[3]);
    msv[1] = make_float4(S[4], S[5], S[6], S[7]);
    msv[2] = make_float4(S[8], S[9], S[10], S[11]);
    msv[3] = make_float4(S[12], S[13], S[14], S[15]);
    if (st) {
      float4* dd_ = (float4*)&DcR[(h * NCH + c) * 64 + kc * 16];
      dd_[0] = make_float4(Pc[0], Pc[1], Pc[2], Pc[3]);
      dd_[1] = make_float4(Pc[4], Pc[5], Pc[6], Pc[7]);
      dd_[2] = make_float4(Pc[8], Pc[9], Pc[10], Pc[11]);
      dd_[3] = make_float4(Pc[12], Pc[13], Pc[14], Pc[15]);
    }
  } else {
    int bb = b - 96;
    int hh = bb >> 4, c = bb & 15;
    float* sbuf = smem;
    int wv = tid >> 6, l = tid & 63;
    int p = wv * 16 + (l & 15);
    int sc = l >> 4;
    int arr = tid >> 6, idx = tid & 63;
    float A = -expf(Alog[hh]);
    float Dph = Dpw[hh];
    int off = (arr == 0) ? (hh * 64 + idx) : (arr == 1) ? (DI + idx) : (DI + DS + idx);
    int t0 = c * CHK;
    float S[16]; float cdA = 1.f;
#pragma unroll
    for (int i = 0; i < 16; i++) S[i] = 0.f;
    float reg = (arr < 3) ? xbc[(size_t)t0 * CONVC + off] : dtb[(size_t)t0 * MH + hh];
    bool st = (wv == 0) && ((l & 15) == 0);   // 4 threads, sc = 0..3, p = 0
    for (int t = 0; t < CHK; ++t) {
      int tt = t0 + t;
      float* cb = sbuf + (t & 1) * 256;
      if (arr < 3) cb[arr * 64 + idx] = reg;
      else if (idx == 0) cb[192] = reg;
      if (t + 1 < CHK) reg = (arr < 3) ? xbc[(size_t)(tt + 1) * CONVC + off]
                                       : dtb[(size_t)(tt + 1) * MH + hh];
      __syncthreads();
      float dt_ = cb[192];
      float dA = expf(dt_ * A);
      cdA *= dA;
      float xp = cb[p];
      float dtx = dt_ * xp;
      float acc = 0.f;
#pragma unroll
      for (int i = 0; i < 16; ++i) {
        int s = sc * 16 + i;
        S[i] = fmaf(dA, S[i], dtx * cb[64 + s]);
        acc = fmaf(S[i], cb[128 + s], acc);
      }
      acc += __shfl_xor(acc, 16);
      acc += __shfl_xor(acc, 32);
      if (l < 16) yb[(size_t)tt * DI + hh * 64 + p] = fmaf(Dph, xp, acc);
      if (st) {
        float4* dst = (float4*)&Ccb[(size_t)tt * DI + hh * 64 + sc * 16];
#pragma unroll
        for (int j4 = 0; j4 < 4; ++j4)
          dst[j4] = make_float4(cdA * cb[128 + sc * 16 + j4 * 4 + 0],
                                cdA * cb[128 + sc * 16 + j4 * 4 + 1],
                                cdA * cb[128 + sc * 16 + j4 * 4 + 2],
                                cdA * cb[128 + sc * 16 + j4 * 4 + 3]);
      }
    }
    // final local state, p-major: Mst[hh][c][p][s]
    float* ms = MstM + (size_t)(hh * NCH + c) * 4096;
    float4* msv = (float4*)&ms[p * 64 + sc * 16];
    msv[0] = make_float4(S[0], S[1], S[2], S[3]);
    msv[1] = make_float4(S[4], S[5], S[6], S[7]);
    msv[2] = make_float4(S[8], S[9], S[10], S[11]);
    msv[3] = make_float4(S[12], S[13], S[14], S[15]);
    if (tid == 0) DcM[hh * NCH + c] = cdA;
  }
}

// ---------------- Phase B: chunk-state combine (elementwise, 16 sequential chunks) ----------------
__global__ __launch_bounds__(256) void combine_kernel(
    const float* __restrict__ MstR, const float* __restrict__ DcR, float* __restrict__ S0R,
    const float* __restrict__ MstM, const float* __restrict__ DcM, float* __restrict__ S0M)
{
  int b = blockIdx.x, tid = threadIdx.x;
  if (b < 96) {
    int h = b >> 4, sub = b & 15;
    int ei = sub * 256 + tid;         // element in [v][k] layout
    int k = ei & 63;
    float S = 0.f;
#pragma unroll
    for (int c = 0; c < NCH; ++c) {
      size_t base = (size_t)(h * NCH + c) * 4096;
      float m = MstR[base + ei];
      float dD = DcR[(h * NCH + c) * 64 + k];
      S0R[base + ei] = S;
      S = fmaf(dD, S, m);
    }
  } else {
    int bb = b - 96;
    int hh = bb >> 4, sub = bb & 15;
    int ei = sub * 256 + tid;
    float S = 0.f;
#pragma unroll
    for (int c = 0; c < NCH; ++c) {
      size_t base = (size_t)(hh * NCH + c) * 4096;
      float m = MstM[base + ei];
      float dD = DcM[hh * NCH + c];
      S0M[base + ei] = S;
      S = fmaf(dD, S, m);
    }
  }
}

// ---------------- Phase C: output correction o += R' @ S0 ----------------
__global__ __launch_bounds__(256) void corr_kernel(
    const float* __restrict__ S0R, const float* __restrict__ rPb, float* __restrict__ so,
    const float* __restrict__ S0M, const float* __restrict__ Ccb, float* __restrict__ yb)
{
  __shared__ float S0l[64 * 68];
  __shared__ float Rl[64 * 68];
  int b = blockIdx.x, tid = threadIdx.x;
  const float* s0g; const float* rg; float* og; int ostride, obase, t0;
  if (b < 96) {
    int h = b >> 4, c = b & 15; t0 = c * CHK;
    s0g = S0R + (size_t)(h * NCH + c) * 4096;   // [v][k]
    rg = rPb; obase = h * 64; ostride = DD; og = so;
  } else {
    int bb = b - 96; int hh = bb >> 4, c = bb & 15; t0 = c * CHK;
    s0g = S0M + (size_t)(hh * NCH + c) * 4096;  // [p][s]
    rg = Ccb; obase = hh * 64; ostride = DI; og = yb;
  }
  // LDS: S0l[inner*68 + outer] (transposed from global [outer][inner])
  for (int gi = tid; gi < 4096; gi += 256)
    S0l[(gi & 63) * 68 + (gi >> 6)] = s0g[gi];
  {
    int t = tid >> 2, q = tid & 3;
    const float4* src = (const float4*)&rg[(size_t)(t0 + t) * ostride + obase + q * 16];
    float4* dst = (float4*)&Rl[t * 68 + q * 16];
    dst[0] = src[0]; dst[1] = src[1]; dst[2] = src[2]; dst[3] = src[3];
  }
  __syncthreads();
  int t = tid >> 2, q = (tid & 3) * 16;
  float acc[16];
#pragma unroll
  for (int j = 0; j < 16; j++) acc[j] = 0.f;
  for (int k = 0; k < 64; ++k) {
    float rv = Rl[t * 68 + k];
    const float4* sp = (const float4*)&S0l[k * 68 + q];
#pragma unroll
    for (int j4 = 0; j4 < 4; ++j4) {
      float4 s4 = sp[j4];
      acc[j4 * 4 + 0] = fmaf(rv, s4.x, acc[j4 * 4 + 0]);
      acc[j4 * 4 + 1] = fmaf(rv, s4.y, acc[j4 * 4 + 1]);
      acc[j4 * 4 + 2] = fmaf(rv, s4.z, acc[j4 * 4 + 2]);
      acc[j4 * 4 + 3] = fmaf(rv, s4.w, acc[j4 * 4 + 3]);
    }
  }
  float4* op = (float4*)&og[(size_t)(t0 + t) * ostride + obase + q];
#pragma unroll
  for (int j4 = 0; j4 < 4; ++j4) {
    float4 cur = op[j4];
    cur.x += acc[j4 * 4 + 0]; cur.y += acc[j4 * 4 + 1];
    cur.z += acc[j4 * 4 + 2]; cur.w += acc[j4 * 4 + 3];
    op[j4] = cur;
  }
}

// ---------------- RWKV groupnorm * silu(g) -> bf16 ----------------
__global__ __launch_bounds__(64) void gn_silu_kernel(const float* __restrict__ ob,
    const float* __restrict__ P, const float* __restrict__ gnw,
    const float* __restrict__ gnb, unsigned short* __restrict__ out)
{
  int row = blockIdx.x;          // t*NH + h
  int t = row / NH, h = row % NH;
  int l = threadIdx.x;
  size_t ix = (size_t)t * DD + h * 64 + l;
  float v = ob[ix];
  float sum = v;
#pragma unroll
  for (int s = 1; s < 64; s <<= 1) sum += __shfl_xor(sum, s);
  float mu = sum * (1.f / 64.f);
  float d = v - mu;
  float vs = d * d;
#pragma unroll
  for (int s = 1; s < 64; s <<= 1) vs += __shfl_xor(vs, s);
  float var = vs * (1.f / 64.f);
  float nrm = d * rsqrtf(var + 1e-5f);
  float gv = P[(size_t)t * PW + 1152 + h * 64 + l];
  out[ix] = f2b(fmaf(nrm, gnw[h * 64 + l], gnb[h * 64 + l]) * siluf(gv));
}

// ---------------- Mamba conv1d (+bias, silu) ----------------
__global__ void conv_kernel(const float* __restrict__ zx, const float* __restrict__ cw,
                            const float* __restrict__ cb, float* __restrict__ out)
{
  int idx = blockIdx.x * 256 + threadIdx.x;
  if (idx >= TT * CONVC) return;
  int t = idx / CONVC, c = idx % CONVC;
  float acc = cb[c];
#pragma unroll
  for (int j = 0; j < 4; ++j) {
    int tt = t + j - 3;
    if (tt >= 0) acc = fmaf(zx[(size_t)tt * XDIM + DI + c], cw[c * 4 + j], acc);
  }
  out[idx] = siluf(acc);
}

// ---------------- dt = softplus(raw + bias) ----------------
__global__ void dt_kernel(const float* __restrict__ zx, const float* __restrict__ dtb,
                          float* __restrict__ out)
{
  int idx = blockIdx.x * 256 + threadIdx.x;
  if (idx < TT * MH) {
    int t = idx / MH, hh = idx % MH;
    float v = zx[(size_t)t * XDIM + (XDIM - MH) + hh] + dtb[hh];
    out[idx] = (v > 20.f) ? v : log1pf(expf(v));
  }
}

// ---------------- Mamba out: rms(y * silu(z), mn_w) -> bf16 ----------------
__global__ __launch_bounds__(256) void mamba_norm_kernel(const float* __restrict__ yb,
    const float* __restrict__ zx, const float* __restrict__ mnw, unsigned short* __restrict__ out)
{
  int t = blockIdx.x;
  __shared__ float vbuf[DI];
  __shared__ float red[256];
  float ss = 0.f;
  for (int c = threadIdx.x; c < DI; c += 256) {
    float z = zx[(size_t)t * XDIM + c];
    float v = yb[(size_t)t * DI + c] * siluf(z);
    vbuf[c] = v;
    ss = fmaf(v, v, ss);
  }
  red[threadIdx.x] = ss; __syncthreads();
  for (int s = 128; s > 0; s >>= 1) {
    if (threadIdx.x < s) red[threadIdx.x] += red[threadIdx.x + s];
    __syncthreads();
  }
  float scale = rsqrtf(red[0] / DI + 1e-6f);
  for (int c = threadIdx.x; c < DI; c += 256)
    out[(size_t)t * DI + c] = f2b(vbuf[c] * scale * mnw[c]);
}

// ---------------- gate combine ----------------
__global__ __launch_bounds__(256) void gate_kernel(const float* __restrict__ orb,
    const float* __restrict__ omb, const float* __restrict__ gw,
    const float* __restrict__ gb, float* __restrict__ h)
{
  int t = blockIdx.x;
  float ss = 0.f;
  for (int c = threadIdx.x; c < DD; c += 256)
    ss += orb[(size_t)t * DD + c] * gw[c] + omb[(size_t)t * DD + c] * gw[DD + c];
  __shared__ float red[256];
  red[threadIdx.x] = ss; __syncthreads();
  for (int s = 128; s > 0; s >>= 1) {
    if (threadIdx.x < s) red[threadIdx.x] += red[threadIdx.x + s];
    __syncthreads();
  }
  float gate = sigmoidf_(red[0] + gb[0]);
  for (int c = threadIdx.x; c < DD; c += 256) {
    size_t ix = (size_t)t * DD + c;
    h[ix] += gate * orb[ix] + (1.f - gate) * omb[ix];
  }
}

// ---------------- gelu (exact) fp32 -> bf16 ----------------
__global__ void gelu_kernel(const float* __restrict__ in, unsigned short* __restrict__ out, int n)
{
  int idx = blockIdx.x * 256 + threadIdx.x;
  if (idx < n) {
    float x = in[idx];
    out[idx] = f2b(0.5f * x * (1.f + erff(x * 0.70710678118654752440f)));
  }
}

__global__ void add_kernel(float* __restrict__ h, const float* __restrict__ t, int n)
{
  int idx = blockIdx.x * 256 + threadIdx.x;
  if (idx < n) h[idx] += t[idx];
}

// ---------------- launcher ----------------
extern "C" void kernel_launch(void* const* d_in, const int* in_sizes, int n_in,
                              void* d_out, int out_size, void* d_ws, size_t ws_size,
                              hipStream_t stream)
{
  const int*   x        = (const int*)  d_in[0];
  const float* embed    = (const float*)d_in[1];
  const float* ln_w     = (const float*)d_in[2];
  const float* Wr       = (const float*)d_in[3];
  const float* Wk       = (const float*)d_in[4];
  const float* Wv       = (const float*)d_in[5];
  const float* Wg       = (const float*)d_in[6];
  const float* Ww       = (const float*)d_in[7];
  const float* w_bias   = (const float*)d_in[8];
  const float* u        = (const float*)d_in[9];
  const float* gn_w     = (const float*)d_in[10];
  const float* gn_b     = (const float*)d_in[11];
  const float* Wo       = (const float*)d_in[12];
  const float* W_in     = (const float*)d_in[13];
  const float* conv_w   = (const float*)d_in[14];
  const float* conv_b   = (const float*)d_in[15];
  const float* dt_bias  = (const float*)d_in[16];
  const float* A_log    = (const float*)d_in[17];
  const float* Dp       = (const float*)d_in[18];
  const float* mn_w     = (const float*)d_in[19];
  const float* W_out    = (const float*)d_in[20];
  const float* gw       = (const float*)d_in[21];
  const float* gb       = (const float*)d_in[22];
  const float* ffn_ln_w = (const float*)d_in[23];
  const float* ffn_w1   = (const float*)d_in[24];
  const float* ffn_w2   = (const float*)d_in[25];
  const float* ln_out_w = (const float*)d_in[26];

  char* base = (char*)d_ws;
  size_t off = 0;
  auto alloc = [&](size_t bytes) { off = (off + 255) & ~(size_t)255; void* p = base + off; off += bytes; return p; };

  float* h    = (float*)alloc((size_t)TT * DD * 4);
  float* P    = (float*)alloc((size_t)TT * PW * 4);
  float* zx   = (float*)alloc((size_t)TT * XDIM * 4);
  float* xb   = (float*)alloc((size_t)TT * CONVC * 4);
  float* dtb  = (float*)alloc((size_t)TT * MH * 4);
  float* yb   = (float*)alloc((size_t)TT * DI * 4);
  float* so   = (float*)alloc((size_t)TT * DD * 4);
  float* orb  = (float*)alloc((size_t)TT * DD * 4);
  float* omb  = (float*)alloc((size_t)TT * DD * 4);
  float* tmp  = (float*)alloc((size_t)TT * DD * 4);
  float* fh   = (float*)alloc((size_t)TT * 1536 * 4);
  float* rPb  = (float*)alloc((size_t)TT * DD * 4);
  float* Ccb  = (float*)alloc((size_t)TT * DI * 4);
  float* MstR = (float*)alloc((size_t)NH * NCH * 4096 * 4);
  float* DcR  = (float*)alloc((size_t)NH * NCH * 64 * 4);
  float* S0R  = (float*)alloc((size_t)NH * NCH * 4096 * 4);
  float* MstM = (float*)alloc((size_t)MH * NCH * 4096 * 4);
  float* DcM  = (float*)alloc((size_t)MH * NCH * 4);
  float* S0M  = (float*)alloc((size_t)MH * NCH * 4096 * 4);
  unsigned short* xnb = (unsigned short*)alloc((size_t)TT * DD * 2);
  unsigned short* gob = (unsigned short*)alloc((size_t)TT * DD * 2);
  unsigned short* ynb = (unsigned short*)alloc((size_t)TT * DI * 2);
  unsigned short* fhb = (unsigned short*)alloc((size_t)TT * 1536 * 2);
  unsigned short* WcatT = (unsigned short*)alloc((size_t)NL * PW * 384 * 2);
  unsigned short* WinT  = (unsigned short*)alloc((size_t)NL * 1728 * 384 * 2);
  unsigned short* WoT   = (unsigned short*)alloc((size_t)NL * 384 * 384 * 2);
  unsigned short* WoutT = (unsigned short*)alloc((size_t)NL * 384 * 768 * 2);
  unsigned short* F1T   = (unsigned short*)alloc((size_t)NL * 1536 * 384 * 2);
  unsigned short* F2T   = (unsigned short*)alloc((size_t)NL * 384 * 1536 * 2);
  unsigned short* embB  = (unsigned short*)alloc((size_t)NV * DD * 2);
  (void)ws_size; (void)in_sizes; (void)n_in; (void)out_size;

  dim3 blk(256);
  int gTD = (TT * DD + 255) / 256;

  // ---- one-time (per launch) weight conversion ----
  const float* Wrkvgw[5] = {Wr, Wk, Wv, Wg, Ww};
  for (int j = 0; j < 5; ++j)
    transconv_kernel<<<dim3(12, 12, 8), blk, 0, stream>>>(
        Wrkvgw[j], WcatT + (size_t)j * 384 * 384, 384, 384, 384,
        (size_t)384 * 384, (size_t)PW * 384);
  transconv_kernel<<<dim3(54, 12, 8), blk, 0, stream>>>(
      W_in, WinT, 384, XDIM, 1728, (size_t)384 * XDIM, (size_t)1728 * 384);
  transconv_kernel<<<dim3(12, 12, 8), blk, 0, stream>>>(
      Wo, WoT, 384, 384, 384, (size_t)384 * 384, (size_t)384 * 384);
  transconv_kernel<<<dim3(12, 24, 8), blk, 0, stream>>>(
      W_out, WoutT, 768, 384, 384, (size_t)768 * 384, (size_t)384 * 768);
  transconv_kernel<<<dim3(48, 12, 8), blk, 0, stream>>>(
      ffn_w1, F1T, 384, 1536, 1536, (size_t)384 * 1536, (size_t)1536 * 384);
  transconv_kernel<<<dim3(12, 48, 8), blk, 0, stream>>>(
      ffn_w2, F2T, 1536, 384, 384, (size_t)1536 * 384, (size_t)384 * 1536);
  conv_b16_kernel<<<(NV * DD + 255) / 256, blk, 0, stream>>>(embed, embB, NV * DD);

  embed_kernel<<<gTD, blk, 0, stream>>>(x, embed, h);

  for (int i = 0; i < NL; ++i) {
    rms_kernel<<<TT, blk, 0, stream>>>(h, ln_w + (size_t)i * DD, xnb, DD, 1e-6f);

    gemm_bf16<<<dim3(30, 16), blk, 0, stream>>>(
        xnb, WcatT + (size_t)i * PW * 384, P, PW, 384, PW);
    decay_kernel<<<gTD, blk, 0, stream>>>(P, w_bias + (size_t)i * DD);

    gemm_bf16<<<dim3(27, 16), blk, 0, stream>>>(
        xnb, WinT + (size_t)i * 1728 * 384, zx, XDIM, 384, XDIM);
    conv_kernel<<<(TT * CONVC + 255) / 256, blk, 0, stream>>>(
        zx, conv_w + (size_t)i * CONVC * 4, conv_b + (size_t)i * CONVC, xb);
    dt_kernel<<<(TT * MH + 255) / 256, blk, 0, stream>>>(zx, dt_bias + (size_t)i * MH, dtb);

    scanA_kernel<<<288, blk, 0, stream>>>(P, u + (size_t)i * NH * 64, so, rPb, MstR, DcR,
                                          xb, dtb, A_log + (size_t)i * MH, Dp + (size_t)i * MH,
                                          yb, Ccb, MstM, DcM);
    combine_kernel<<<288, blk, 0, stream>>>(MstR, DcR, S0R, MstM, DcM, S0M);
    corr_kernel<<<288, blk, 0, stream>>>(S0R, rPb, so, S0M, Ccb, yb);

    gn_silu_kernel<<<TT * NH, dim3(64), 0, stream>>>(so, P, gn_w + (size_t)i * DD,
                                                     gn_b + (size_t)i * DD, gob);
    gemm_bf16<<<dim3(6, 16), blk, 0, stream>>>(
        gob, WoT + (size_t)i * 384 * 384, orb, DD, 384, DD);

    mamba_norm_kernel<<<TT, blk, 0, stream>>>(yb, zx, mn_w + (size_t)i * DI, ynb);
    gemm_bf16<<<dim3(6, 16), blk, 0, stream>>>(
        ynb, WoutT + (size_t)i * 384 * 768, omb, DD, 768, DD);

    gate_kernel<<<TT, blk, 0, stream>>>(orb, omb, gw + (size_t)i * 2 * DD, gb + i, h);

    rms_kernel<<<TT, blk, 0, stream>>>(h, ffn_ln_w + (size_t)i * DD, xnb, DD, 1e-6f);
    gemm_bf16<<<dim3(24, 16), blk, 0, stream>>>(
        xnb, F1T + (size_t)i * 1536 * 384, fh, 1536, 384, 1536);
    gelu_kernel<<<(TT * 1536 + 255) / 256, blk, 0, stream>>>(fh, fhb, TT * 1536);
    gemm_bf16<<<dim3(6, 16), blk, 0, stream>>>(
        fhb, F2T + (size_t)i * 384 * 1536, tmp, DD, 1536, DD);
    add_kernel<<<gTD, blk, 0, stream>>>(h, tmp, TT * DD);
  }

  rms_kernel<<<TT, blk, 0, stream>>>(h, ln_out_w, xnb, DD, 1e-6f);
  gemm_bf16<<<dim3(500, 16), blk, 0, stream>>>(
      xnb, embB, (float*)d_out, NV, 384, NV);
}